// Round 7
// baseline (315.877 us; speedup 1.0000x reference)
//
#include <hip/hip_runtime.h>

typedef short short8 __attribute__((ext_vector_type(8)));
typedef float f32x4 __attribute__((ext_vector_type(4)));
typedef unsigned short ushort8_t __attribute__((ext_vector_type(8)));

#define O_CH 128
#define I_CH 128
#define HW 112
#define PLANE (HW * HW)        // 12544
#define COLS 56                // output cols per WG
#define NSTG 66                // staged col capacity (64 padded + 2 halo; cols 58..65 garbage-only)
#define BUFB (3 * NSTG * 64)   // bytes per LDS buffer = 12672

__device__ __forceinline__ unsigned short f2bf(float f) {
  union { float f; unsigned u; } v; v.f = f;
  unsigned r = v.u + 0x7FFFu + ((v.u >> 16) & 1u);   // RNE (weights only)
  return (unsigned short)(r >> 16);
}

// one-instruction truncate-pack: [lo,hi] floats -> packed bf16 pair
__device__ __forceinline__ unsigned pktrunc(float lo, float hi) {
  union { float f; unsigned u; } a, b; a.f = lo; b.f = hi;
  return __builtin_amdgcn_perm(b.u, a.u, 0x07060302u);
}

__global__ void wsynth_kernel(const float* __restrict__ core,
                              const float* __restrict__ periph,
                              const float* __restrict__ thr,
                              const float* __restrict__ scale,
                              unsigned short* __restrict__ Wb) {
  int idx = blockIdx.x * blockDim.x + threadIdx.x;   // o*128 + i
  if (idx >= O_CH * I_CH) return;
  int o = idx >> 7;
  float c = core[idx];
  float s = scale[0];
  float g = 1.0f / (1.0f + __expf(-s * (fabsf(c) - thr[o])));
#pragma unroll
  for (int tap = 0; tap < 9; ++tap) {
    float p  = (tap == 4) ? 1.0f : periph[tap < 4 ? tap : tap - 1];
    float gg = (tap == 4) ? 1.0f : g;
    Wb[tap * (O_CH * I_CH) + idx] = f2bf(c * p * gg);   // layout [tap][o][i]
  }
}

__global__ __launch_bounds__(256, 4)
void conv_kernel(const float* __restrict__ X,
                 const unsigned short* __restrict__ Wb,
                 float* __restrict__ Out) {
  // 2 buffers x [row 0..2][col 0..65][32 ch] bf16. col-row = 64 B = 4 slots of 16 B.
  // Conflict-free slot swizzle (derived): slot' = grp ^ ((s>>1)&3)
  //   write wave (64 cols x 1 grp): addr/16 mod 8 = (4s + w(s)) mod 8 uniform -> 8 lanes/group
  //   read wave (16 cols x 4 lk4):  4 slots per col spread over groups      -> 8 lanes/group
  __shared__ unsigned short Xs[2 * 3 * NSTG * 32];   // 25,344 B -> 6 WGs/CU
  char* lds = (char*)Xs;

  // XCD-chunked swizzle: 7168 = 8 XCDs x 896 contiguous logical ids
  const int bid = blockIdx.x;
  const int L = (bid & 7) * 896 + (bid >> 3);
  const int b = L / 224;
  const int rem = L - b * 224;
  const int y = rem >> 1;
  const int cb = (rem & 1) * COLS;     // output col base: 0 or 56

  const int t   = threadIdx.x;
  const int wv  = t >> 6;              // wave 0..3 -> o quarter
  const int l   = t & 63;
  const int ln  = l & 15;              // MFMA frag lane (col)
  const int lk4 = l >> 4;              // k-slice 0..3

  // staging coords: 64 cols x 4 ch-groups of 8
  const int s    = t & 63;             // staged col index
  const int grp  = t >> 6;             // ch-group 0..3
  const int icol = cb - 1 + s;         // input col
  const bool sok = (s < 58);           // only cols 0..57 are real
  const int wslot = grp ^ ((s >> 1) & 3);

  f32x4 acc[2][4];
#pragma unroll
  for (int mr = 0; mr < 2; ++mr)
#pragma unroll
    for (int nf = 0; nf < 4; ++nf)
      acc[mr][nf] = (f32x4)0.0f;

#define LOAD8(V, KCH, SUB)                                                      \
  {                                                                             \
    const int row_ = y + (SUB)-1;                                               \
    const bool ok_ = (row_ >= 0) && (row_ < HW) && (icol >= 0) && (icol < HW);  \
    const float* sp_ = X + ((size_t)(b * I_CH + (KCH) + grp * 8) * HW + row_)   \
                       * HW + icol;                                             \
    _Pragma("unroll") for (int j = 0; j < 8; ++j) V[j] = 0.0f;                  \
    if (ok_) {                                                                  \
      _Pragma("unroll") for (int j = 0; j < 8; ++j) V[j] = sp_[j * PLANE];      \
    }                                                                           \
  }

#define WRITE8(V, SUB, WB)                                                      \
  if (sok) {                                                                    \
    union { ushort8_t v8; unsigned u[4]; } pk_;                                 \
    pk_.u[0] = pktrunc(V[0], V[1]);                                             \
    pk_.u[1] = pktrunc(V[2], V[3]);                                             \
    pk_.u[2] = pktrunc(V[4], V[5]);                                             \
    pk_.u[3] = pktrunc(V[6], V[7]);                                             \
    *reinterpret_cast<ushort8_t*>((WB) + ((SUB)*NSTG + s) * 64 + wslot * 16) = pk_.v8; \
  }

#define COMPUTE_SUB(SUB, RB, K)                                                 \
  _Pragma("unroll") for (int dx = 0; dx < 3; ++dx) {                            \
    const int tap_ = (SUB)*3 + dx;                                              \
    const unsigned short* wp_ = Wb + tap_ * (O_CH * I_CH)                       \
                              + (wv * 32 + ln) * I_CH + (K)*32 + lk4 * 8;       \
    short8 a0_ = *reinterpret_cast<const short8*>(wp_);                         \
    short8 a1_ = *reinterpret_cast<const short8*>(wp_ + 16 * I_CH);             \
    const int q_ = dx + ln;                                                     \
    const int rslot_ = lk4 ^ ((q_ >> 1) & 3);   /* nf-invariant: +16 is even */ \
    const char* bp_ = (RB) + ((SUB)*NSTG + q_) * 64 + rslot_ * 16;              \
    _Pragma("unroll") for (int nf = 0; nf < 4; ++nf) {                          \
      short8 bb_ = *reinterpret_cast<const short8*>(bp_ + nf * (16 * 64));      \
      acc[0][nf] = __builtin_amdgcn_mfma_f32_16x16x32_bf16(a0_, bb_, acc[0][nf], 0, 0, 0); \
      acc[1][nf] = __builtin_amdgcn_mfma_f32_16x16x32_bf16(a1_, bb_, acc[1][nf], 0, 0, 0); \
    }                                                                           \
  }

  // ---- prologue: stage chunk 0 (channels 0..31) into buffer 0 ----
  {
    float P0[8], P1[8], P2[8];
    LOAD8(P0, 0, 0)
    LOAD8(P1, 0, 1)
    LOAD8(P2, 0, 2)
    WRITE8(P0, 0, lds)
    WRITE8(P1, 1, lds)
    WRITE8(P2, 2, lds)
  }
  __syncthreads();

  // ---- main loop: 4 chunks of 32 channels, double-buffered, lag-1 writes ----
#pragma unroll
  for (int k = 0; k < 4; ++k) {
    char* rbuf = lds + (k & 1) * BUFB;
    char* wbuf = lds + ((k & 1) ^ 1) * BUFB;
    float LA[8], LB[8];

    // sub 0: issue loads for (k+1, sub0); compute sub0
    if (k < 3) LOAD8(LA, (k + 1) * 32, 0)
    COMPUTE_SUB(0, rbuf, k)

    // sub 1: issue loads for (k+1, sub1); compute sub1; write sub0 (lag-1)
    if (k < 3) LOAD8(LB, (k + 1) * 32, 1)
    COMPUTE_SUB(1, rbuf, k)
    if (k < 3) WRITE8(LA, 0, wbuf)

    // sub 2: issue loads for (k+1, sub2); compute sub2; write sub1, sub2
    if (k < 3) LOAD8(LA, (k + 1) * 32, 2)
    COMPUTE_SUB(2, rbuf, k)
    if (k < 3) {
      WRITE8(LB, 1, wbuf)
      WRITE8(LA, 2, wbuf)
      __syncthreads();
    }
  }

  // ---- epilogue: C/D map col=lane&15, row=(lane>>4)*4+j; mask padded cols ----
  const int obase = wv * 32 + lk4 * 4;
  float* outp = Out + (size_t)b * O_CH * PLANE + (size_t)y * HW + cb;
#pragma unroll
  for (int mr = 0; mr < 2; ++mr) {
#pragma unroll
    for (int j = 0; j < 4; ++j) {
      const int o = obase + mr * 16 + j;
      float* po = outp + (size_t)o * PLANE;
#pragma unroll
      for (int nf = 0; nf < 4; ++nf) {
        if (nf < 3 || ln < 8) {            // cols cb+0..55 only
          po[nf * 16 + ln] = acc[mr][nf][j];
        }
      }
    }
  }
}

extern "C" void kernel_launch(void* const* d_in, const int* in_sizes, int n_in,
                              void* d_out, int out_size, void* d_ws, size_t ws_size,
                              hipStream_t stream) {
  const float* x      = (const float*)d_in[0];
  const float* core   = (const float*)d_in[1];
  const float* periph = (const float*)d_in[2];
  const float* thr    = (const float*)d_in[3];
  const float* scale  = (const float*)d_in[4];
  unsigned short* Wb  = (unsigned short*)d_ws;   // 9*128*128*2 = 294,912 B

  wsynth_kernel<<<(O_CH * I_CH + 255) / 256, 256, 0, stream>>>(core, periph, thr, scale, Wb);

  const int grid = 32 * HW * 2;   // one WG per (batch, row, col-half) = 7168
  conv_kernel<<<grid, 256, 0, stream>>>(x, Wb, (float*)d_out);
}

// Round 8
// 272.273 us; speedup vs baseline: 1.1602x; 1.1602x over previous
//
#include <hip/hip_runtime.h>

typedef short short8 __attribute__((ext_vector_type(8)));
typedef float f32x4 __attribute__((ext_vector_type(4)));
typedef unsigned short ushort8_t __attribute__((ext_vector_type(8)));

#define O_CH 128
#define I_CH 128
#define HW 112
#define PLANE (HW * HW)      // 12544
#define NCOL 114             // 112 cols + 2 halo
#define SLOTB (NCOL * 64)    // bytes per row-slot: 114 cols x 32ch x 2B = 7296

__device__ __forceinline__ unsigned short f2bf(float f) {
  union { float f; unsigned u; } v; v.f = f;
  unsigned r = v.u + 0x7FFFu + ((v.u >> 16) & 1u);   // RNE (weights only)
  return (unsigned short)(r >> 16);
}

// one-instruction truncate-pack: [lo,hi] floats -> packed bf16 pair
__device__ __forceinline__ unsigned pktrunc(float lo, float hi) {
  union { float f; unsigned u; } a, b; a.f = lo; b.f = hi;
  return __builtin_amdgcn_perm(b.u, a.u, 0x07060302u);
}

__global__ void wsynth_kernel(const float* __restrict__ core,
                              const float* __restrict__ periph,
                              const float* __restrict__ thr,
                              const float* __restrict__ scale,
                              unsigned short* __restrict__ Wb) {
  int idx = blockIdx.x * blockDim.x + threadIdx.x;   // o*128 + i
  if (idx >= O_CH * I_CH) return;
  int o = idx >> 7;
  float c = core[idx];
  float s = scale[0];
  float g = 1.0f / (1.0f + __expf(-s * (fabsf(c) - thr[o])));
#pragma unroll
  for (int tap = 0; tap < 9; ++tap) {
    float p  = (tap == 4) ? 1.0f : periph[tap < 4 ? tap : tap - 1];
    float gg = (tap == 4) ? 1.0f : g;
    Wb[tap * (O_CH * I_CH) + idx] = f2bf(c * p * gg);   // layout [tap][o][i]
  }
}

__global__ __launch_bounds__(256, 4)
void conv_kernel(const float* __restrict__ X,
                 const unsigned short* __restrict__ Wb,
                 float* __restrict__ Out) {
  // 4-slot row ring: slot = [114 cols][32 ch] bf16; col-row = 64 B = 4 chunks of 16 B.
  // Conflict-free slot swizzle (R7-verified, 0 conflicts): slot' = chgrp ^ ((col>>1)&3)
  __shared__ unsigned short Xs[4 * NCOL * 32];   // 29,184 B -> 4 WGs/CU
  char* lds = (char*)Xs;

  // XCD-chunked swizzle: 3584 = 8 XCDs x 448 (R6-verified: FETCH 599->106 MB)
  const int bid = blockIdx.x;
  const int L = (bid & 7) * 448 + (bid >> 3);
  const int b = L / HW;
  const int y = L - b * HW;

  const int t   = threadIdx.x;
  const int wv  = t >> 6;              // wave 0..3 -> o quarter
  const int l   = t & 63;
  const int ln  = l & 15;              // MFMA frag lane
  const int lk4 = l >> 4;              // k-slice 0..3

  // staging coords: 128 cols x 2 ch-halves of 16
  const int col  = t & 127;            // staged col (input col + 1)
  const int half = t >> 7;             // 0..1
  const int icol = col - 1;
  const bool cok = (col < NCOL);
  const int wsw  = (col >> 1) & 3;     // write swizzle

  f32x4 acc[2][7];
#pragma unroll
  for (int mr = 0; mr < 2; ++mr)
#pragma unroll
    for (int nf = 0; nf < 7; ++nf)
      acc[mr][nf] = (f32x4)0.0f;

  // ---- target phase t: row = y-1+(t%3), channels = (t/3)*32 ----
#define LOAD16(V, TP)                                                           \
  {                                                                             \
    const int row_ = y + ((TP) % 3) - 1;                                        \
    const bool ok_ = (row_ >= 0) && (row_ < HW) && (icol >= 0) && (icol < HW);  \
    const float* sp_ = X + ((size_t)(b * I_CH + ((TP) / 3) * 32 + half * 16)    \
                            * HW + row_) * HW + icol;                           \
    _Pragma("unroll") for (int j = 0; j < 16; ++j) V[j] = 0.0f;                 \
    if (ok_) {                                                                  \
      _Pragma("unroll") for (int j = 0; j < 16; ++j) V[j] = sp_[j * PLANE];     \
    }                                                                           \
  }

#define WRITE16(V, TP)                                                          \
  if (cok) {                                                                    \
    char* base_ = lds + ((TP) & 3) * SLOTB + col * 64;                          \
    _Pragma("unroll") for (int q = 0; q < 2; ++q) {                             \
      union { ushort8_t s; unsigned u[4]; } pk_;                                \
      pk_.u[0] = pktrunc(V[q * 8 + 0], V[q * 8 + 1]);                           \
      pk_.u[1] = pktrunc(V[q * 8 + 2], V[q * 8 + 3]);                           \
      pk_.u[2] = pktrunc(V[q * 8 + 4], V[q * 8 + 5]);                           \
      pk_.u[3] = pktrunc(V[q * 8 + 6], V[q * 8 + 7]);                           \
      const int slot_ = (half * 2 + q) ^ wsw;                                   \
      *reinterpret_cast<ushort8_t*>(base_ + slot_ * 16) = pk_.s;                \
    }                                                                           \
  }

#define COMPUTE_PHASE(P)                                                        \
  {                                                                             \
    const char* sb_ = lds + ((P) & 3) * SLOTB;                                  \
    __builtin_amdgcn_s_setprio(1);                                              \
    _Pragma("unroll") for (int dx = 0; dx < 3; ++dx) {                          \
      const int tap_ = ((P) % 3) * 3 + dx;                                      \
      const unsigned short* wp_ = Wb + tap_ * (O_CH * I_CH)                     \
                                + (wv * 32 + ln) * I_CH + ((P) / 3) * 32        \
                                + lk4 * 8;                                      \
      short8 a0_ = *reinterpret_cast<const short8*>(wp_);                       \
      short8 a1_ = *reinterpret_cast<const short8*>(wp_ + 16 * I_CH);           \
      const int q_ = dx + ln;                                                   \
      const int rslot_ = lk4 ^ ((q_ >> 1) & 3);   /* nf stride 16: invariant */ \
      const char* bp_ = sb_ + q_ * 64 + rslot_ * 16;                            \
      _Pragma("unroll") for (int nf = 0; nf < 7; ++nf) {                        \
        short8 bb_ = *reinterpret_cast<const short8*>(bp_ + nf * 1024);         \
        acc[0][nf] = __builtin_amdgcn_mfma_f32_16x16x32_bf16(a0_, bb_, acc[0][nf], 0, 0, 0); \
        acc[1][nf] = __builtin_amdgcn_mfma_f32_16x16x32_bf16(a1_, bb_, acc[1][nf], 0, 0, 0); \
      }                                                                         \
    }                                                                           \
    __builtin_amdgcn_s_setprio(0);                                              \
  }

#define RING_BARRIER()                                                          \
  {                                                                             \
    asm volatile("s_waitcnt lgkmcnt(0)" ::: "memory");                          \
    __builtin_amdgcn_s_barrier();                                               \
    __builtin_amdgcn_sched_barrier(0);                                          \
  }

  float LD[16];   // in-flight staging row (consumed next phase)

  // ---- prologue: stage targets 0,1,2 into slots 0,1,2; issue LD for target 3 ----
  {
    float P0[16];
    LOAD16(P0, 0) WRITE16(P0, 0)
    LOAD16(P0, 1) WRITE16(P0, 1)
    LOAD16(P0, 2) WRITE16(P0, 2)
  }
  LOAD16(LD, 3)
  RING_BARRIER()

  // ---- 12 phases: {issue ld(p+4); compute p; write ld -> target p+3; barrier} ----
#pragma unroll
  for (int p = 0; p < 12; ++p) {
    float NL[16];
    if (p <= 7) LOAD16(NL, p + 4)          // issue early: covered by this phase's MFMAs
    COMPUTE_PHASE(p)
    if (p <= 8) WRITE16(LD, p + 3)         // consume load issued last phase
    if (p <= 7) {
#pragma unroll
      for (int j = 0; j < 16; ++j) LD[j] = NL[j];
    }
    if (p <= 10) RING_BARRIER()
  }

  // ---- epilogue: C/D map col=lane&15, row=(lane>>4)*4+j ----
  const int obase = wv * 32 + lk4 * 4;
  float* outp = Out + (size_t)b * O_CH * PLANE + (size_t)y * HW;
#pragma unroll
  for (int mr = 0; mr < 2; ++mr) {
#pragma unroll
    for (int j = 0; j < 4; ++j) {
      const int o = obase + mr * 16 + j;
      float* po = outp + (size_t)o * PLANE;
#pragma unroll
      for (int nf = 0; nf < 7; ++nf) {
        po[nf * 16 + ln] = acc[mr][nf][j];
      }
    }
  }
}

extern "C" void kernel_launch(void* const* d_in, const int* in_sizes, int n_in,
                              void* d_out, int out_size, void* d_ws, size_t ws_size,
                              hipStream_t stream) {
  const float* x      = (const float*)d_in[0];
  const float* core   = (const float*)d_in[1];
  const float* periph = (const float*)d_in[2];
  const float* thr    = (const float*)d_in[3];
  const float* scale  = (const float*)d_in[4];
  unsigned short* Wb  = (unsigned short*)d_ws;   // 9*128*128*2 = 294,912 B

  wsynth_kernel<<<(O_CH * I_CH + 255) / 256, 256, 0, stream>>>(core, periph, thr, scale, Wb);

  const int grid = 32 * HW;   // one WG per (batch, output row) = 3584
  conv_kernel<<<grid, 256, 0, stream>>>(x, Wb, (float*)d_out);
}

// Round 9
// 204.759 us; speedup vs baseline: 1.5427x; 1.3297x over previous
//
#include <hip/hip_runtime.h>

typedef short short8 __attribute__((ext_vector_type(8)));
typedef float f32x4 __attribute__((ext_vector_type(4)));
typedef unsigned short ushort8_t __attribute__((ext_vector_type(8)));

#define O_CH 128
#define I_CH 128
#define HW 112
#define PLANE (HW * HW)        // 12544
#define NCOL 114               // 112 cols + 2 halo
#define BUFB (3 * NCOL * 64)   // bytes per LDS buffer: 3 rows * 114 cols * 32ch * 2B

__device__ __forceinline__ unsigned short f2bf(float f) {
  union { float f; unsigned u; } v; v.f = f;
  unsigned r = v.u + 0x7FFFu + ((v.u >> 16) & 1u);   // RNE (weights only)
  return (unsigned short)(r >> 16);
}

// one-instruction truncate-pack: [lo,hi] floats -> packed bf16 pair
__device__ __forceinline__ unsigned pktrunc(float lo, float hi) {
  union { float f; unsigned u; } a, b; a.f = lo; b.f = hi;
  return __builtin_amdgcn_perm(b.u, a.u, 0x07060302u);
}

__global__ void wsynth_kernel(const float* __restrict__ core,
                              const float* __restrict__ periph,
                              const float* __restrict__ thr,
                              const float* __restrict__ scale,
                              unsigned short* __restrict__ Wb) {
  int idx = blockIdx.x * blockDim.x + threadIdx.x;   // o*128 + i
  if (idx >= O_CH * I_CH) return;
  int o = idx >> 7;
  float c = core[idx];
  float s = scale[0];
  float g = 1.0f / (1.0f + __expf(-s * (fabsf(c) - thr[o])));
#pragma unroll
  for (int tap = 0; tap < 9; ++tap) {
    float p  = (tap == 4) ? 1.0f : periph[tap < 4 ? tap : tap - 1];
    float gg = (tap == 4) ? 1.0f : g;
    Wb[tap * (O_CH * I_CH) + idx] = f2bf(c * p * gg);   // layout [tap][o][i]
  }
}

__global__ __launch_bounds__(256, 3)
void conv_kernel(const float* __restrict__ X,
                 const unsigned short* __restrict__ Wb,
                 float* __restrict__ Out) {
  // 2 buffers x [row 0..2][col 0..113][32 ch] bf16; col-row = 64 B = 4 slots of 16 B.
  // Conflict-free slot swizzle (R7/R8-verified, 0 conflicts): slot' = chgrp ^ ((col>>1)&3)
  __shared__ unsigned short Xs[2 * 3 * NCOL * 32];   // 43,776 B -> 3 WGs/CU
  char* lds = (char*)Xs;

  // XCD-chunked swizzle: 3584 = 8 XCDs x 448 (R6-verified: FETCH 599->106 MB)
  const int bid = blockIdx.x;
  const int L = (bid & 7) * 448 + (bid >> 3);
  const int b = L / HW;
  const int y = L - b * HW;

  const int t   = threadIdx.x;
  const int wv  = t >> 6;              // wave 0..3 -> o quarter
  const int l   = t & 63;
  const int ln  = l & 15;              // MFMA frag lane
  const int lk4 = l >> 4;              // k-slice 0..3

  // staging coords
  const int c    = t & 127;            // staged col (input col + 1)
  const int chb  = (t >> 7) * 16;      // local channel base: 0 or 16
  const int icol = c - 1;
  const bool cok = (c < NCOL);
  const int wxor = (c >> 1) & 3;       // verified conflict-free write swizzle

  f32x4 acc[2][7];
#pragma unroll
  for (int mr = 0; mr < 2; ++mr)
#pragma unroll
    for (int nf = 0; nf < 7; ++nf)
      acc[mr][nf] = (f32x4)0.0f;

  // per-wave weight base (invariant)
  const unsigned short* wbase = Wb + (wv * 32 + ln) * I_CH + lk4 * 8;

#define LOAD16(V, KCH, SUB)                                                     \
  {                                                                             \
    const int row_ = y + (SUB)-1;                                               \
    const bool ok_ = (row_ >= 0) && (row_ < HW) && (icol >= 0) && (icol < HW);  \
    const float* sp_ = X + ((size_t)(b * I_CH + (KCH) + chb) * HW + row_) * HW  \
                       + icol;                                                  \
    _Pragma("unroll") for (int j = 0; j < 16; ++j) V[j] = 0.0f;                 \
    if (ok_) {                                                                  \
      _Pragma("unroll") for (int j = 0; j < 16; ++j) V[j] = sp_[j * PLANE];     \
    }                                                                           \
  }

#define WRITE16(V, SUB, WB)                                                     \
  if (cok) {                                                                    \
    const int base_ = ((SUB)*NCOL + c) * 64;                                    \
    _Pragma("unroll") for (int q = 0; q < 2; ++q) {                             \
      union { ushort8_t s; unsigned u[4]; } pk_;                                \
      pk_.u[0] = pktrunc(V[q * 8 + 0], V[q * 8 + 1]);                           \
      pk_.u[1] = pktrunc(V[q * 8 + 2], V[q * 8 + 3]);                           \
      pk_.u[2] = pktrunc(V[q * 8 + 4], V[q * 8 + 5]);                           \
      pk_.u[3] = pktrunc(V[q * 8 + 6], V[q * 8 + 7]);                           \
      const int slot_ = ((chb >> 3) + q) ^ wxor;                                \
      *reinterpret_cast<ushort8_t*>((WB) + base_ + slot_ * 16) = pk_.s;         \
    }                                                                           \
  }

  // A-fragment prefetch for global phase Q (Q = chunk*3 + sub, 0..11):
  //   tap set = (Q%3)*3 + dx, k-chunk = Q/3
#define APFETCH(D0, D1, Q)                                                      \
  _Pragma("unroll") for (int dx = 0; dx < 3; ++dx) {                            \
    const unsigned short* wp_ = wbase + (((Q) % 3) * 3 + dx) * (O_CH * I_CH)    \
                              + ((Q) / 3) * 32;                                 \
    D0[dx] = *reinterpret_cast<const short8*>(wp_);                             \
    D1[dx] = *reinterpret_cast<const short8*>(wp_ + 16 * I_CH);                 \
  }

#define COMPUTE_SUB_REG(SUB, RB, S0, S1)                                        \
  _Pragma("unroll") for (int dx = 0; dx < 3; ++dx) {                            \
    const int q_ = dx + ln;                                                     \
    const int rslot_ = lk4 ^ ((q_ >> 1) & 3);   /* nf stride 16: invariant */   \
    const char* bp_ = (RB) + ((SUB)*NCOL + q_) * 64 + rslot_ * 16;              \
    _Pragma("unroll") for (int nf = 0; nf < 7; ++nf) {                          \
      short8 bb_ = *reinterpret_cast<const short8*>(bp_ + nf * 1024);           \
      acc[0][nf] = __builtin_amdgcn_mfma_f32_16x16x32_bf16(S0[dx], bb_, acc[0][nf], 0, 0, 0); \
      acc[1][nf] = __builtin_amdgcn_mfma_f32_16x16x32_bf16(S1[dx], bb_, acc[1][nf], 0, 0, 0); \
    }                                                                           \
  }

  short8 A0[3], A1[3], N0[3], N1[3];   // current / next A-fragment sets

  // ---- prologue: stage chunk 0 into buffer 0; prefetch A for phase 0 ----
  {
    float P0[16], P1[16], P2[16];
    LOAD16(P0, 0, 0)
    LOAD16(P1, 0, 1)
    LOAD16(P2, 0, 2)
    APFETCH(A0, A1, 0)
    WRITE16(P0, 0, lds)
    WRITE16(P1, 1, lds)
    WRITE16(P2, 2, lds)
  }
  __syncthreads();

  // ---- main loop: 4 chunks, double-buffered, lag-1 writes, A prefetched 1 sub ahead ----
#pragma unroll
  for (int k = 0; k < 4; ++k) {
    char* rbuf = lds + (k & 1) * BUFB;
    char* wbuf = lds + ((k & 1) ^ 1) * BUFB;
    float LA[16], LB[16];
    const int q0 = k * 3;

    // sub 0: stage-load (k+1,0); prefetch A(q0+1); compute sub0
    if (k < 3) LOAD16(LA, (k + 1) * 32, 0)
    APFETCH(N0, N1, q0 + 1)
    COMPUTE_SUB_REG(0, rbuf, A0, A1)
#pragma unroll
    for (int dx = 0; dx < 3; ++dx) { A0[dx] = N0[dx]; A1[dx] = N1[dx]; }

    // sub 1: stage-load (k+1,1); prefetch A(q0+2); compute sub1; write sub0 (lag-1)
    if (k < 3) LOAD16(LB, (k + 1) * 32, 1)
    APFETCH(N0, N1, q0 + 2)
    COMPUTE_SUB_REG(1, rbuf, A0, A1)
    if (k < 3) WRITE16(LA, 0, wbuf)
#pragma unroll
    for (int dx = 0; dx < 3; ++dx) { A0[dx] = N0[dx]; A1[dx] = N1[dx]; }

    // sub 2: stage-load (k+1,2); prefetch A(q0+3); compute sub2; write sub1,2
    if (k < 3) LOAD16(LA, (k + 1) * 32, 2)
    if (k < 3) APFETCH(N0, N1, q0 + 3)
    COMPUTE_SUB_REG(2, rbuf, A0, A1)
    if (k < 3) {
      WRITE16(LB, 1, wbuf)
      WRITE16(LA, 2, wbuf)
#pragma unroll
      for (int dx = 0; dx < 3; ++dx) { A0[dx] = N0[dx]; A1[dx] = N1[dx]; }
      __syncthreads();
    }
  }

  // ---- epilogue: C/D map col=lane&15, row=(lane>>4)*4+j ----
  const int obase = wv * 32 + lk4 * 4;
  float* outp = Out + (size_t)b * O_CH * PLANE + (size_t)y * HW;
#pragma unroll
  for (int mr = 0; mr < 2; ++mr) {
#pragma unroll
    for (int j = 0; j < 4; ++j) {
      const int o = obase + mr * 16 + j;
      float* po = outp + (size_t)o * PLANE;
#pragma unroll
      for (int nf = 0; nf < 7; ++nf) {
        po[nf * 16 + ln] = acc[mr][nf][j];
      }
    }
  }
}

extern "C" void kernel_launch(void* const* d_in, const int* in_sizes, int n_in,
                              void* d_out, int out_size, void* d_ws, size_t ws_size,
                              hipStream_t stream) {
  const float* x      = (const float*)d_in[0];
  const float* core   = (const float*)d_in[1];
  const float* periph = (const float*)d_in[2];
  const float* thr    = (const float*)d_in[3];
  const float* scale  = (const float*)d_in[4];
  unsigned short* Wb  = (unsigned short*)d_ws;   // 9*128*128*2 = 294,912 B

  wsynth_kernel<<<(O_CH * I_CH + 255) / 256, 256, 0, stream>>>(core, periph, thr, scale, Wb);

  const int grid = 32 * HW;   // one WG per (batch, output row) = 3584
  conv_kernel<<<grid, 256, 0, stream>>>(x, Wb, (float*)d_out);
}